// Round 10
// baseline (197.203 us; speedup 1.0000x reference)
//
#include <hip/hip_runtime.h>
#include <hip/hip_bf16.h>
#include <stdint.h>

// ---- problem constants ----
#define C_CLS  100000
#define DDIM   512
#define BROWS  512
#define BN     128         // classes per block
#define NSTEP  16          // K steps of 32
#define EPSN   1e-5f

typedef __attribute__((ext_vector_type(8))) short short8;
typedef __attribute__((ext_vector_type(4))) float f32x4;

// d_ws float layout:
//   [0    .. 4096)  : 256 gemm accumulation slots, stride 16 floats
//   [4096 .. 5120)  : 64 label accumulation slots, stride 16 floats
//   byte 32768 ...  : xn — normalized input, bf16 ROW-MAJOR [512][512] (512 KB)

__device__ inline unsigned pk2(float a, float b) {
  __hip_bfloat162 h = __float22bfloat162_rn(make_float2(a, b));
  unsigned u; __builtin_memcpy(&u, &h, 4); return u;
}

// Normalize each input row -> bf16 row-major. Also zero ws accumulation slots.
__global__ void __launch_bounds__(64) k_norm_input(const float* __restrict__ in,
                                                   uint4* __restrict__ xn,
                                                   float* __restrict__ ws) {
  int b = blockIdx.x;
  int lane = threadIdx.x;              // covers k = lane*8 .. +7
  if (lane == 0) {
    if (b < 256) ws[b * 16] = 0.f;
    else if (b < 320) ws[4096 + (b - 256) * 16] = 0.f;
  }
  const float4* row = (const float4*)(in + b * DDIM);
  float4 v0 = row[lane * 2];
  float4 v1 = row[lane * 2 + 1];
  float ss = v0.x*v0.x + v0.y*v0.y + v0.z*v0.z + v0.w*v0.w
           + v1.x*v1.x + v1.y*v1.y + v1.z*v1.z + v1.w*v1.w;
#pragma unroll
  for (int o = 32; o >= 1; o >>= 1) ss += __shfl_xor(ss, o, 64);
  float sc = 1.f / fmaxf(sqrtf(ss), EPSN);
  uint4 o4;
  o4.x = pk2(v0.x*sc, v0.y*sc);
  o4.y = pk2(v0.z*sc, v0.w*sc);
  o4.z = pk2(v1.x*sc, v1.y*sc);
  o4.w = pk2(v1.z*sc, v1.w*sc);
  xn[b * 64 + lane] = o4;
}

// Fused GEMM + loss. 512 threads (8 waves), block tile 512 rows x 128 cls,
// wave tile 128 x 64 (32 MFMA / K32-step). BOTH operands DMA'd to LDS via
// global_load_lds (pre-swizzled sources, frag-cell layout), 3-buffer rotation,
// one barrier/step preceded by counted s_waitcnt vmcnt(6) — never 0 in loop.
// W staged as f32, cvt to bf16 in-register at consume (also yields norms).
__global__ void __launch_bounds__(512, 2)
k_gemm(const uint4* __restrict__ xn, const float* __restrict__ wt,
       const float* __restrict__ bias, float* __restrict__ ws) {
  __shared__ __align__(16) unsigned char sA[3][32768];  // bf16 frag cells
  __shared__ __align__(16) unsigned char sW[3][16384];  // f32 frag cells
  __shared__ float sRed[8];

  const int tid  = threadIdx.x;
  const int lane = tid & 63;
  const int wv   = tid >> 6;          // 0..7
  const int mw   = wv >> 1;           // M-group: rows [mw*128, +128)
  const int nw   = wv & 1;            // N-group: cls  [nw*64, +64) within tile
  const int r16  = lane & 15;
  const int kh   = lane >> 4;         // 0..3 k-chunk
  const unsigned char* xnb = (const unsigned char*)xn;

  // DMA one K-step: A 32 KB (4 instrs/wave), W f32 16 KB (2 instrs/wave).
  // LDS cell (16B): A: m*64 + kh*16 + (r^kh)  [m=row/16]
  //                 W: (n*8+kq)*16 + (r^(kq&3)) [n=cls/16, kq=k-quad 0..7]
  // Sources pre-swizzled so the linear gload_lds dest realizes these layouts.
  auto dma = [&](int s, int buf) {
#pragma unroll
    for (int i = 0; i < 4; ++i) {
      int m = wv * 4 + i;
      int row = m * 16 + (r16 ^ kh);
      const unsigned char* src = xnb + row * 1024 + s * 64 + kh * 16;
      __builtin_amdgcn_global_load_lds(
          (const __attribute__((address_space(1))) unsigned int*)src,
          (__attribute__((address_space(3))) unsigned int*)(sA[buf] + m * 1024),
          16, 0, 0);
    }
#pragma unroll
    for (int i = 0; i < 2; ++i) {
      int kq = i * 4 + kh;
      int cls = blockIdx.x * BN + wv * 16 + (r16 ^ (kq & 3));
      if (cls >= C_CLS) cls = C_CLS - 1;       // clamp; masked in epilogue
      const unsigned char* src =
          (const unsigned char*)(wt + (size_t)cls * DDIM) + s * 128 + kq * 16;
      __builtin_amdgcn_global_load_lds(
          (const __attribute__((address_space(1))) unsigned int*)src,
          (__attribute__((address_space(3))) unsigned int*)(sW[buf] + wv * 2048 + i * 1024),
          16, 0, 0);
    }
  };

  float wsq[4] = {0.f, 0.f, 0.f, 0.f};
  f32x4 acc[8][4];
#pragma unroll
  for (int i = 0; i < 8; ++i)
#pragma unroll
    for (int j = 0; j < 4; ++j) acc[i][j] = (f32x4)(0.f);

  auto consume = [&](int buf) {
    const unsigned char* Ab = sA[buf];
    const unsigned char* Wb = sW[buf];
    short8 af[8];
#pragma unroll
    for (int i = 0; i < 8; ++i) {
      int m = mw * 8 + i;
      af[i] = *(const short8*)(Ab + (m * 64 + kh * 16 + (r16 ^ kh)) * 16);
    }
    const int kq0 = kh * 2, kq1 = kh * 2 + 1;
#pragma unroll
    for (int j = 0; j < 4; ++j) {
      int n = nw * 4 + j;
      float4 b0 = *(const float4*)(Wb + ((n * 8 + kq0) * 16 + (r16 ^ (kq0 & 3))) * 16);
      float4 b1 = *(const float4*)(Wb + ((n * 8 + kq1) * 16 + (r16 ^ (kq1 & 3))) * 16);
      wsq[j] += b0.x*b0.x + b0.y*b0.y + b0.z*b0.z + b0.w*b0.w
              + b1.x*b1.x + b1.y*b1.y + b1.z*b1.z + b1.w*b1.w;
      uint4 u;
      u.x = pk2(b0.x, b0.y); u.y = pk2(b0.z, b0.w);
      u.z = pk2(b1.x, b1.y); u.w = pk2(b1.z, b1.w);
      short8 wf; __builtin_memcpy(&wf, &u, 16);
#pragma unroll
      for (int i = 0; i < 8; ++i)
        acc[i][j] = __builtin_amdgcn_mfma_f32_16x16x32_bf16(af[i], wf, acc[i][j], 0, 0, 0);
    }
  };

  // prologue: steps 0 and 1 in flight; wait for step 0 only (vmcnt(6)).
  dma(0, 0);
  dma(1, 1);
  asm volatile("s_waitcnt vmcnt(6)" ::: "memory");
  __builtin_amdgcn_s_barrier();

#pragma unroll 1
  for (int s = 0; s < NSTEP; ++s) {
    if (s < NSTEP - 2) dma(s + 2, (s + 2) % 3);
    consume(s % 3);
    if (s < NSTEP - 1) {
      __builtin_amdgcn_sched_barrier(0);
      if (s < NSTEP - 2) asm volatile("s_waitcnt vmcnt(6)" ::: "memory");
      else               asm volatile("s_waitcnt vmcnt(0)" ::: "memory");
      __builtin_amdgcn_s_barrier();
    }
  }

  // ---- epilogue: finish norms (2 shfl), loss over 128 elems/thread ----
  const float bv = bias[0];
  float lsum = 0.f;
#pragma unroll
  for (int j = 0; j < 4; ++j) {
    float t = wsq[j];
    t += __shfl_xor(t, 16, 64);
    t += __shfl_xor(t, 32, 64);                 // 4 k-groups summed
    float s64 = 64.f / fmaxf(sqrtf(t), EPSN);   // fold S and 1/||w||
    bool valid = (blockIdx.x * BN + (nw * 4 + j) * 16 + r16) < C_CLS;
#pragma unroll
    for (int i = 0; i < 8; ++i) {
#pragma unroll
      for (int e = 0; e < 4; ++e) {
        // x = 64*cos - bias <= ~51: upper clamp provably inactive; lower
        // clip irrelevant (exp underflow). log1p(z) ~= z - z^2/2, z<=1/32.
        float x = fmaf(acc[i][j][e], s64, -bv);
        float z = __expf(x);
        float l = fmaf(-0.5f * z, z, z);
        if (z > 0.03125f) l = __logf(1.f + z);  // rare (~1e-4)
        lsum += valid ? l : 0.f;
      }
    }
  }
#pragma unroll
  for (int o = 32; o >= 1; o >>= 1) lsum += __shfl_xor(lsum, o, 64);
  if (lane == 0) sRed[wv] = lsum;
  __syncthreads();
  if (tid == 0) {
    float t = 0.f;
#pragma unroll
    for (int i = 0; i < 8; i++) t += sRed[i];
    atomicAdd(&ws[(blockIdx.x & 255) * 16], t);
  }
}

// Label correction: replace n_loss(b, label_b) by p_loss(b, label_b), full f32.
__global__ void __launch_bounds__(64) k_label(const float* __restrict__ in,
                                              const float* __restrict__ wt,
                                              const int* __restrict__ label,
                                              const float* __restrict__ bias,
                                              float* __restrict__ ws) {
  int b = blockIdx.x;
  int lane = threadIdx.x;
  int c = label[b];
  const float4* xr = (const float4*)(in + b * DDIM);
  const float4* wr = (const float4*)(wt + (size_t)c * DDIM);
  float dt = 0.f, sx = 0.f, sw = 0.f;
#pragma unroll
  for (int i = 0; i < 2; i++) {
    float4 x = xr[lane * 2 + i];
    float4 w = wr[lane * 2 + i];
    dt += x.x*w.x + x.y*w.y + x.z*w.z + x.w*w.w;
    sx += x.x*x.x + x.y*x.y + x.z*x.z + x.w*x.w;
    sw += w.x*w.x + w.y*w.y + w.z*w.z + w.w*w.w;
  }
#pragma unroll
  for (int o = 32; o >= 1; o >>= 1) {
    dt += __shfl_xor(dt, o, 64);
    sx += __shfl_xor(sx, o, 64);
    sw += __shfl_xor(sw, o, 64);
  }
  if (lane == 0) {
    float bv = bias[0];
    float cosv = dt / (fmaxf(sqrtf(sx), EPSN) * fmaxf(sqrtf(sw), EPSN));
    float cp = 64.f * (cosv - 0.4f) - bv;
    cp = fminf(fmaxf(cp, -64.f), 64.f);
    float pl = log1pf(expf(-cp));
    float cn = 64.f * cosv - bv;
    cn = fminf(fmaxf(cn, -64.f), 64.f);
    float nl = log1pf(expf(cn));
    atomicAdd(&ws[4096 + (b & 63) * 16], pl - nl);
  }
}

// Merge the 256 gemm slots + 64 label slots, scale by 1/B.
__global__ void __launch_bounds__(64) k_final(const float* __restrict__ ws,
                                              float* __restrict__ out) {
  int lane = threadIdx.x;
  float s = ws[lane * 16] + ws[(lane + 64) * 16]
          + ws[(lane + 128) * 16] + ws[(lane + 192) * 16]
          + ws[4096 + lane * 16];
#pragma unroll
  for (int o = 32; o >= 1; o >>= 1) s += __shfl_xor(s, o, 64);
  if (lane == 0) out[0] = s * (1.f / 512.f);
}

extern "C" void kernel_launch(void* const* d_in, const int* in_sizes, int n_in,
                              void* d_out, int out_size, void* d_ws, size_t ws_size,
                              hipStream_t stream) {
  const float* input  = (const float*)d_in[0];
  const int*   label  = (const int*)d_in[1];
  const float* weight = (const float*)d_in[2];
  const float* bias   = (const float*)d_in[3];
  float* out = (float*)d_out;
  float* ws  = (float*)d_ws;
  uint4* xn  = (uint4*)((char*)d_ws + 32768);

  k_norm_input<<<BROWS, 64, 0, stream>>>(input, xn, ws);
  k_gemm<<<(C_CLS + BN - 1) / BN, 512, 0, stream>>>(xn, weight, bias, ws);
  k_label<<<BROWS, 64, 0, stream>>>(input, weight, label, bias, ws);
  k_final<<<1, 64, 0, stream>>>(ws, out);
}

// Round 11
// 143.891 us; speedup vs baseline: 1.3705x; 1.3705x over previous
//
#include <hip/hip_runtime.h>
#include <hip/hip_bf16.h>
#include <stdint.h>

// ---- problem constants ----
#define C_CLS  100000
#define DDIM   512
#define BROWS  512
#define BN     128         // classes per block
#define NSTEP  16          // K steps of 32
#define EPSN   1e-5f

typedef __attribute__((ext_vector_type(8))) short short8;
typedef __attribute__((ext_vector_type(4))) float f32x4;

// d_ws float layout:
//   [0    .. 4096)  : 256 gemm accumulation slots, stride 16 floats
//   [4096 .. 5120)  : 64 label accumulation slots, stride 16 floats
//   byte 32768 ...  : xnf — bf16 A in MFMA fragment layout (512 KB)

__device__ inline unsigned pk2(float a, float b) {
  __hip_bfloat162 h = __float22bfloat162_rn(make_float2(a, b));
  unsigned u; __builtin_memcpy(&u, &h, 4); return u;
}

// Normalize each input row -> bf16, fragment order:
// cell idx (16B) = (s*32 + r16)*64 + khalf*16 + row; s=k>>5, r16=b>>4,
// khalf=(k>>3)&3, row=b&15. One K-step = contiguous 32KB. Zero ws slots.
__global__ void __launch_bounds__(64) k_norm_input(const float* __restrict__ in,
                                                   uint4* __restrict__ xnf,
                                                   float* __restrict__ ws) {
  int b = blockIdx.x;
  int lane = threadIdx.x;              // lane covers k = lane*8 .. +7
  if (lane == 0) {
    if (b < 256) ws[b * 16] = 0.f;
    else if (b < 320) ws[4096 + (b - 256) * 16] = 0.f;
  }
  const float4* row = (const float4*)(in + b * DDIM);
  float4 v0 = row[lane * 2];
  float4 v1 = row[lane * 2 + 1];
  float ss = v0.x*v0.x + v0.y*v0.y + v0.z*v0.z + v0.w*v0.w
           + v1.x*v1.x + v1.y*v1.y + v1.z*v1.z + v1.w*v1.w;
#pragma unroll
  for (int o = 32; o >= 1; o >>= 1) ss += __shfl_xor(ss, o, 64);
  float sc = 1.f / fmaxf(sqrtf(ss), EPSN);
  uint4 o4;
  o4.x = pk2(v0.x*sc, v0.y*sc);
  o4.y = pk2(v0.z*sc, v0.w*sc);
  o4.z = pk2(v1.x*sc, v1.y*sc);
  o4.w = pk2(v1.z*sc, v1.w*sc);
  int idx = ((lane >> 2) * 32 + (b >> 4)) * 64 + (lane & 3) * 16 + (b & 15);
  xnf[idx] = o4;
}

// Fused GEMM + loss. 512 threads (8 waves), block = 512 rows x BN=128 cls,
// wave = 128 rows x 64 cls (32 MFMA / K32-step). A: linear coalesced
// global_load_lds DMA (frag-ordered xnf, contiguous 32KB/step), 2-buffer.
// W: HBM->reg (2-step lead) -> cvt bf16 -> frag-layout LDS (XOR swizzle),
// 2-buffer. One raw barrier/step with counted vmcnt(2) — never 0 mid-loop.
__global__ void __launch_bounds__(512, 2)
k_gemm(const uint4* __restrict__ xnf, const float* __restrict__ wt,
       const float* __restrict__ bias, float* __restrict__ ws) {
  __shared__ __align__(16) unsigned char sA[2][32768];
  __shared__ __align__(16) unsigned char sW[2][8192];
  __shared__ float sNsq[BN];
  __shared__ float sRed[8];

  const int tid  = threadIdx.x;
  const int lane = tid & 63;
  const int wv   = tid >> 6;
  const int mw   = wv >> 1;            // rows [mw*128, +128)
  const int nw   = wv & 1;             // cls  [nw*64, +64)
  const int cbase = blockIdx.x * BN;

  // W staging: thread t -> class scls = t>>2 (0..127), k-octet skh = t&3.
  // frag cell (nf*64 + skh*16 + (c16^skh)); XOR spreads write banks 4-way.
  const int scls = tid >> 2;
  const int skh  = tid & 3;
  int wcls = cbase + scls;
  if (wcls >= C_CLS) wcls = C_CLS - 1;          // clamp; masked in epilogue
  const float* wsrc = wt + (size_t)wcls * DDIM + skh * 8;   // + s*32
  const int wbyte = ((scls >> 4) * 64 + skh * 16 + ((scls & 15) ^ skh)) * 16;

  const uint4* asrc = xnf + wv * 256 + lane;    // + s*2048 + i*64

  float wsq = 0.f;
  f32x4 acc[8][4];
#pragma unroll
  for (int i = 0; i < 8; ++i)
#pragma unroll
    for (int j = 0; j < 4; ++j) acc[i][j] = (f32x4)(0.f);

  auto dmaA = [&](int s, int buf) {
#pragma unroll
    for (int i = 0; i < 4; ++i) {
      const uint4* src = asrc + s * 2048 + i * 64;       // coalesced 1KB
      __builtin_amdgcn_global_load_lds(
          (const __attribute__((address_space(1))) unsigned int*)src,
          (__attribute__((address_space(3))) unsigned int*)(sA[buf] + wv * 4096 + i * 1024),
          16, 0, 0);
    }
  };
  auto cvtW = [&](const float4& a, const float4& b, int buf) {
    wsq += a.x*a.x + a.y*a.y + a.z*a.z + a.w*a.w
         + b.x*b.x + b.y*b.y + b.z*b.z + b.w*b.w;
    uint4 u;
    u.x = pk2(a.x, a.y); u.y = pk2(a.z, a.w);
    u.z = pk2(b.x, b.y); u.w = pk2(b.z, b.w);
    *(uint4*)(sW[buf] + wbyte) = u;
  };
  auto consume = [&](int buf) {
    const unsigned char* Ab = sA[buf];
    const unsigned char* Wb = sW[buf];
    const int rswz = lane ^ ((lane >> 4) & 3);
    short8 af[8];
#pragma unroll
    for (int i = 0; i < 8; ++i)
      af[i] = *(const short8*)(Ab + ((mw * 8 + i) * 64 + lane) * 16);
#pragma unroll
    for (int j = 0; j < 4; ++j) {
      short8 wf = *(const short8*)(Wb + ((nw * 4 + j) * 64 + rswz) * 16);
#pragma unroll
      for (int i = 0; i < 8; ++i)
        acc[i][j] = __builtin_amdgcn_mfma_f32_16x16x32_bf16(af[i], wf, acc[i][j], 0, 0, 0);
    }
  };
  auto stepwait2 = [&]() {
    asm volatile("s_waitcnt vmcnt(2) lgkmcnt(0)" ::: "memory");
    __builtin_amdgcn_s_barrier();
  };
  auto stepwait0 = [&]() {
    asm volatile("s_waitcnt vmcnt(0) lgkmcnt(0)" ::: "memory");
    __builtin_amdgcn_s_barrier();
  };

  // prologue: A(0) DMA first; W(0),W(1),W(2) loads queued; cvt W(0)->buf0
  // (its auto vmcnt wait also covers the A(0) DMA, which is older).
  dmaA(0, 0);
  float4 w0a = *(const float4*)(wsrc);
  float4 w0b = *(const float4*)(wsrc + 4);
  float4 wAa = *(const float4*)(wsrc + 32), wAb = *(const float4*)(wsrc + 36);
  float4 wBa = *(const float4*)(wsrc + 64), wBb = *(const float4*)(wsrc + 68);
  cvtW(w0a, w0b, 0);
  asm volatile("s_waitcnt lgkmcnt(0)" ::: "memory");
  __builtin_amdgcn_s_barrier();

  // steps 0..11: uniform full pipeline (dma s+1, consume s, write W(s+1),
  // reload reg with W(s+3)/W(s+4)); steps 12..15 peeled with tail guards.
#pragma unroll 1
  for (int s2 = 0; s2 < 6; ++s2) {
    const int s0 = 2 * s2;
    dmaA(s0 + 1, 1);
    consume(0);
    cvtW(wAa, wAb, 1);                               // writes W(s0+1)
    wAa = *(const float4*)(wsrc + (s0 + 3) * 32);
    wAb = *(const float4*)(wsrc + (s0 + 3) * 32 + 4);
    stepwait2();
    dmaA(s0 + 2, 0);
    consume(1);
    cvtW(wBa, wBb, 0);                               // writes W(s0+2)
    wBa = *(const float4*)(wsrc + (s0 + 4) * 32);
    wBb = *(const float4*)(wsrc + (s0 + 4) * 32 + 4);
    stepwait2();
  }
  // s = 12
  dmaA(13, 1);
  consume(0);
  cvtW(wAa, wAb, 1);                                 // W(13)
  wAa = *(const float4*)(wsrc + 15 * 32);
  wAb = *(const float4*)(wsrc + 15 * 32 + 4);
  stepwait2();
  // s = 13
  dmaA(14, 0);
  consume(1);
  cvtW(wBa, wBb, 0);                                 // W(14)
  stepwait0();
  // s = 14
  dmaA(15, 1);
  consume(0);
  cvtW(wAa, wAb, 1);                                 // W(15)
  stepwait0();
  // s = 15
  consume(1);

  // ---- per-class norm^2: 4 staging threads share a class ----
  wsq += __shfl_xor(wsq, 1, 64);
  wsq += __shfl_xor(wsq, 2, 64);
  if (skh == 0) sNsq[scls] = wsq;
  __syncthreads();

  // ---- epilogue: loss over 128 acc elements / thread ----
  const float bv = bias[0];
  float lsum = 0.f;
#pragma unroll
  for (int j = 0; j < 4; ++j) {
    int cl = (nw * 4 + j) * 16 + (lane & 15);
    float s64 = 64.f / fmaxf(sqrtf(sNsq[cl]), EPSN);   // fold S and 1/||w||
    bool valid = (cbase + cl) < C_CLS;
#pragma unroll
    for (int i = 0; i < 8; ++i) {
#pragma unroll
      for (int e = 0; e < 4; ++e) {
        // x = 64*cos - bias <= ~51: upper clamp provably inactive; lower
        // clip irrelevant (exp underflow). log1p(z) ~= z - z^2/2, z<=1/32.
        float x = fmaf(acc[i][j][e], s64, -bv);
        float z = __expf(x);
        float l = fmaf(-0.5f * z, z, z);
        if (z > 0.03125f) l = __logf(1.f + z);  // rare (~1e-4)
        lsum += valid ? l : 0.f;
      }
    }
  }
#pragma unroll
  for (int o = 32; o >= 1; o >>= 1) lsum += __shfl_xor(lsum, o, 64);
  if (lane == 0) sRed[wv] = lsum;
  __syncthreads();
  if (tid == 0) {
    float t = 0.f;
#pragma unroll
    for (int i = 0; i < 8; i++) t += sRed[i];
    atomicAdd(&ws[(blockIdx.x & 255) * 16], t);
  }
}

// Label correction: replace n_loss(b, label_b) by p_loss(b, label_b), full f32.
__global__ void __launch_bounds__(64) k_label(const float* __restrict__ in,
                                              const float* __restrict__ wt,
                                              const int* __restrict__ label,
                                              const float* __restrict__ bias,
                                              float* __restrict__ ws) {
  int b = blockIdx.x;
  int lane = threadIdx.x;
  int c = label[b];
  const float4* xr = (const float4*)(in + b * DDIM);
  const float4* wr = (const float4*)(wt + (size_t)c * DDIM);
  float dt = 0.f, sx = 0.f, sw = 0.f;
#pragma unroll
  for (int i = 0; i < 2; i++) {
    float4 x = xr[lane * 2 + i];
    float4 w = wr[lane * 2 + i];
    dt += x.x*w.x + x.y*w.y + x.z*w.z + x.w*w.w;
    sx += x.x*x.x + x.y*x.y + x.z*x.z + x.w*x.w;
    sw += w.x*w.x + w.y*w.y + w.z*w.z + w.w*w.w;
  }
#pragma unroll
  for (int o = 32; o >= 1; o >>= 1) {
    dt += __shfl_xor(dt, o, 64);
    sx += __shfl_xor(sx, o, 64);
    sw += __shfl_xor(sw, o, 64);
  }
  if (lane == 0) {
    float bv = bias[0];
    float cosv = dt / (fmaxf(sqrtf(sx), EPSN) * fmaxf(sqrtf(sw), EPSN));
    float cp = 64.f * (cosv - 0.4f) - bv;
    cp = fminf(fmaxf(cp, -64.f), 64.f);
    float pl = log1pf(expf(-cp));
    float cn = 64.f * cosv - bv;
    cn = fminf(fmaxf(cn, -64.f), 64.f);
    float nl = log1pf(expf(cn));
    atomicAdd(&ws[4096 + (b & 63) * 16], pl - nl);
  }
}

// Merge the 256 gemm slots + 64 label slots, scale by 1/B.
__global__ void __launch_bounds__(64) k_final(const float* __restrict__ ws,
                                              float* __restrict__ out) {
  int lane = threadIdx.x;
  float s = ws[lane * 16] + ws[(lane + 64) * 16]
          + ws[(lane + 128) * 16] + ws[(lane + 192) * 16]
          + ws[4096 + lane * 16];
#pragma unroll
  for (int o = 32; o >= 1; o >>= 1) s += __shfl_xor(s, o, 64);
  if (lane == 0) out[0] = s * (1.f / 512.f);
}

extern "C" void kernel_launch(void* const* d_in, const int* in_sizes, int n_in,
                              void* d_out, int out_size, void* d_ws, size_t ws_size,
                              hipStream_t stream) {
  const float* input  = (const float*)d_in[0];
  const int*   label  = (const int*)d_in[1];
  const float* weight = (const float*)d_in[2];
  const float* bias   = (const float*)d_in[3];
  float* out = (float*)d_out;
  float* ws  = (float*)d_ws;
  uint4* xnf = (uint4*)((char*)d_ws + 32768);

  k_norm_input<<<BROWS, 64, 0, stream>>>(input, xnf, ws);
  k_gemm<<<(C_CLS + BN - 1) / BN, 512, 0, stream>>>(xnf, weight, bias, ws);
  k_label<<<BROWS, 64, 0, stream>>>(input, weight, label, bias, ws);
  k_final<<<1, 64, 0, stream>>>(ws, out);
}

// Round 12
// 143.789 us; speedup vs baseline: 1.3715x; 1.0007x over previous
//
#include <hip/hip_runtime.h>
#include <hip/hip_bf16.h>
#include <stdint.h>

// ---- problem constants ----
#define C_CLS  100000
#define DDIM   512
#define BROWS  512
#define NT     64          // classes per tile
#define QK     64          // K per quarter (2 MFMA K-steps)
#define EPSN   1e-5f
#define NBLK   256         // persistent blocks (1 per CU)

typedef __attribute__((ext_vector_type(8))) short short8;
typedef __attribute__((ext_vector_type(4))) float f32x4;

// d_ws float layout:
//   [0    .. 4096)  : 256 gemm accumulation slots, stride 16 floats
//   [4096 .. 5120)  : 64 label accumulation slots, stride 16 floats
//   byte 32768 ...  : xnf — bf16 A in MFMA fragment layout (512 KB)

__device__ inline unsigned pk2(float a, float b) {
  __hip_bfloat162 h = __float22bfloat162_rn(make_float2(a, b));
  unsigned u; __builtin_memcpy(&u, &h, 4); return u;
}

// Normalize each input row -> bf16, fragment order:
// cell idx (16B) = (s*32 + r16)*64 + khalf*16 + row; s=k>>5, r16=b>>4,
// khalf=(k>>3)&3, row=b&15. Also zeroes the ws accumulation slots.
__global__ void __launch_bounds__(64) k_norm_input(const float* __restrict__ in,
                                                   uint4* __restrict__ xnf,
                                                   float* __restrict__ ws) {
  int b = blockIdx.x;
  int lane = threadIdx.x;              // lane covers k = lane*8 .. +7
  if (lane == 0) {
    if (b < 256) ws[b * 16] = 0.f;
    else if (b < 320) ws[4096 + (b - 256) * 16] = 0.f;
  }
  const float4* row = (const float4*)(in + b * DDIM);
  float4 v0 = row[lane * 2];
  float4 v1 = row[lane * 2 + 1];
  float ss = v0.x*v0.x + v0.y*v0.y + v0.z*v0.z + v0.w*v0.w
           + v1.x*v1.x + v1.y*v1.y + v1.z*v1.z + v1.w*v1.w;
#pragma unroll
  for (int o = 32; o >= 1; o >>= 1) ss += __shfl_xor(ss, o, 64);
  float sc = 1.f / fmaxf(sqrtf(ss), EPSN);
  uint4 o4;
  o4.x = pk2(v0.x*sc, v0.y*sc);
  o4.y = pk2(v0.z*sc, v0.w*sc);
  o4.z = pk2(v1.x*sc, v1.y*sc);
  o4.w = pk2(v1.z*sc, v1.w*sc);
  int idx = ((lane >> 2) * 32 + (b >> 4)) * 64 + (lane & 3) * 16 + (b & 15);
  xnf[idx] = o4;
}

// Fused GEMM + loss, producer/consumer wave specialization.
// 768 threads: waves 0..7 = consumers (512 rows x 64 cls, wave 64x64,
// A from L2 to regs, W f32 from LDS ring, cvt in-reg, MFMA);
// waves 8..11 = producers (pure global_load_lds W-f32 stream into a
// 4 x 16KB ring, 2-quarter lead, counted vmcnt(4), never drained mid-loop).
// Separate waves => separate in-order vmcnt queues => no serialization.
// W rows DMA'd with granule^row permutation within each 256B row span
// (coalesced) so consumer column reads are bank-conflict-free.
__global__ void __launch_bounds__(768, 3)
k_gemm(const uint4* __restrict__ xnf, const float* __restrict__ wt,
       const float* __restrict__ bias, float* __restrict__ ws) {
  __shared__ __align__(16) unsigned char sWq[4][16384];  // [cls 0..63][256B]

  const int tid  = threadIdx.x;
  const int lane = tid & 63;
  const int wv   = tid >> 6;                    // 0..11
  const int nt   = (blockIdx.x < 27) ? 7 : 6;   // 1563 = 6*256 + 27
  const int Q    = nt * 8;

  if (wv >= 8) {
    // ---------------- producers ----------------
    const int pw = wv - 8;                      // 0..3
    const int rl = lane >> 4;                   // row-in-group
    const int g  = lane & 15;                   // dest granule (16B)
    auto issue = [&](int gq) {
      const int it = gq >> 3, q = gq & 7;
      const int cb = (blockIdx.x + it * NBLK) * NT;
      unsigned char* dstb = sWq[gq & 3];
#pragma unroll
      for (int i = 0; i < 4; ++i) {
        int r = pw * 16 + i * 4 + rl;
        int cls = cb + r;
        if (cls >= C_CLS) cls = C_CLS - 1;      // clamp; masked in epilogue
        const float* src = wt + (size_t)cls * DDIM + q * QK + ((g ^ (r & 15)) << 2);
        __builtin_amdgcn_global_load_lds(
            (const __attribute__((address_space(1))) unsigned int*)src,
            (__attribute__((address_space(3))) unsigned int*)(dstb + (pw * 16 + i * 4) * 256),
            16, 0, 0);
      }
    };
    issue(0);
    if (Q > 1) issue(1);
    asm volatile("s_waitcnt vmcnt(4)" ::: "memory");   // q0 landed; q1 in flight
    __builtin_amdgcn_s_barrier();
#pragma unroll 1
    for (int gq = 0; gq < Q; ++gq) {
      if (gq + 2 < Q) {
        issue(gq + 2);
        asm volatile("s_waitcnt vmcnt(4)" ::: "memory"); // gq+1 landed, gq+2 flies
      } else {
        asm volatile("s_waitcnt vmcnt(0)" ::: "memory"); // tail drain
      }
      __builtin_amdgcn_s_barrier();
    }
  } else {
    // ---------------- consumers ----------------
    const int r16 = lane & 15;
    const int kg  = lane >> 4;                  // k-group 0..3
    const uint4* abase = xnf + wv * 256 + lane; // + s*2048 + m*64
    const float bv = bias[0];
    float lsum = 0.f;
    __builtin_amdgcn_s_barrier();               // matches producer prologue
#pragma unroll 1
    for (int it = 0; it < nt; ++it) {
      const int cbase = (blockIdx.x + it * NBLK) * NT;
      float wsq[4] = {0.f, 0.f, 0.f, 0.f};
      f32x4 acc[4][4];
#pragma unroll
      for (int m = 0; m < 4; ++m)
#pragma unroll
        for (int j = 0; j < 4; ++j) acc[m][j] = (f32x4)(0.f);
#pragma unroll 1
      for (int q = 0; q < 8; ++q) {
        const unsigned char* buf = sWq[(it * 8 + q) & 3];
#pragma unroll
        for (int sl = 0; sl < 2; ++sl) {
          const int s = q * 2 + sl;
          short8 af[4];
#pragma unroll
          for (int m = 0; m < 4; ++m)
            af[m] = *(const short8*)(abase + s * 2048 + m * 64);
          const int g0 = sl * 8 + kg * 2;
#pragma unroll
          for (int j = 0; j < 4; ++j) {
            const int row = j * 16 + r16;
            const unsigned char* rp = buf + row * 256;
            float4 b0 = *(const float4*)(rp + ((g0 ^ (row & 15)) << 4));
            float4 b1 = *(const float4*)(rp + (((g0 + 1) ^ (row & 15)) << 4));
            wsq[j] += b0.x*b0.x + b0.y*b0.y + b0.z*b0.z + b0.w*b0.w
                    + b1.x*b1.x + b1.y*b1.y + b1.z*b1.z + b1.w*b1.w;
            uint4 u;
            u.x = pk2(b0.x, b0.y); u.y = pk2(b0.z, b0.w);
            u.z = pk2(b1.x, b1.y); u.w = pk2(b1.z, b1.w);
            short8 wf; __builtin_memcpy(&wf, &u, 16);
#pragma unroll
            for (int m = 0; m < 4; ++m)
              acc[m][j] = __builtin_amdgcn_mfma_f32_16x16x32_bf16(af[m], wf, acc[m][j], 0, 0, 0);
          }
        }
        __builtin_amdgcn_s_barrier();
        __builtin_amdgcn_sched_barrier(0);      // no hoisting across the ring
      }
      // ---- tile epilogue: finish norms (2 shfl), loss, accumulate ----
#pragma unroll
      for (int j = 0; j < 4; ++j) {
        float t = wsq[j];
        t += __shfl_xor(t, 16, 64);
        t += __shfl_xor(t, 32, 64);
        float s64 = 64.f / fmaxf(sqrtf(t), EPSN);   // fold S and 1/||w||
        bool valid = (cbase + j * 16 + r16) < C_CLS;
#pragma unroll
        for (int m = 0; m < 4; ++m) {
#pragma unroll
          for (int e = 0; e < 4; ++e) {
            // x = 64*cos - bias <= ~51: upper clamp provably inactive; lower
            // clip irrelevant (exp underflow). log1p(z) ~= z - z^2/2, z<=1/32.
            float x = fmaf(acc[m][j][e], s64, -bv);
            float z = __expf(x);
            float l = fmaf(-0.5f * z, z, z);
            if (z > 0.03125f) l = __logf(1.f + z);  // rare (~1e-4)
            lsum += valid ? l : 0.f;
          }
        }
      }
    }
#pragma unroll
    for (int o = 32; o >= 1; o >>= 1) lsum += __shfl_xor(lsum, o, 64);
    if (lane == 0)
      atomicAdd(&ws[(((blockIdx.x << 3) + wv) & 255) * 16], lsum);
  }
}

// Label correction: replace n_loss(b, label_b) by p_loss(b, label_b), full f32.
__global__ void __launch_bounds__(64) k_label(const float* __restrict__ in,
                                              const float* __restrict__ wt,
                                              const int* __restrict__ label,
                                              const float* __restrict__ bias,
                                              float* __restrict__ ws) {
  int b = blockIdx.x;
  int lane = threadIdx.x;
  int c = label[b];
  const float4* xr = (const float4*)(in + b * DDIM);
  const float4* wr = (const float4*)(wt + (size_t)c * DDIM);
  float dt = 0.f, sx = 0.f, sw = 0.f;
#pragma unroll
  for (int i = 0; i < 2; i++) {
    float4 x = xr[lane * 2 + i];
    float4 w = wr[lane * 2 + i];
    dt += x.x*w.x + x.y*w.y + x.z*w.z + x.w*w.w;
    sx += x.x*x.x + x.y*x.y + x.z*x.z + x.w*x.w;
    sw += w.x*w.x + w.y*w.y + w.z*w.z + w.w*w.w;
  }
#pragma unroll
  for (int o = 32; o >= 1; o >>= 1) {
    dt += __shfl_xor(dt, o, 64);
    sx += __shfl_xor(sx, o, 64);
    sw += __shfl_xor(sw, o, 64);
  }
  if (lane == 0) {
    float bv = bias[0];
    float cosv = dt / (fmaxf(sqrtf(sx), EPSN) * fmaxf(sqrtf(sw), EPSN));
    float cp = 64.f * (cosv - 0.4f) - bv;
    cp = fminf(fmaxf(cp, -64.f), 64.f);
    float pl = log1pf(expf(-cp));
    float cn = 64.f * cosv - bv;
    cn = fminf(fmaxf(cn, -64.f), 64.f);
    float nl = log1pf(expf(cn));
    atomicAdd(&ws[4096 + (b & 63) * 16], pl - nl);
  }
}

// Merge the 256 gemm slots + 64 label slots, scale by 1/B.
__global__ void __launch_bounds__(64) k_final(const float* __restrict__ ws,
                                              float* __restrict__ out) {
  int lane = threadIdx.x;
  float s = ws[lane * 16] + ws[(lane + 64) * 16]
          + ws[(lane + 128) * 16] + ws[(lane + 192) * 16]
          + ws[4096 + lane * 16];
#pragma unroll
  for (int o = 32; o >= 1; o >>= 1) s += __shfl_xor(s, o, 64);
  if (lane == 0) out[0] = s * (1.f / 512.f);
}

extern "C" void kernel_launch(void* const* d_in, const int* in_sizes, int n_in,
                              void* d_out, int out_size, void* d_ws, size_t ws_size,
                              hipStream_t stream) {
  const float* input  = (const float*)d_in[0];
  const int*   label  = (const int*)d_in[1];
  const float* weight = (const float*)d_in[2];
  const float* bias   = (const float*)d_in[3];
  float* out = (float*)d_out;
  float* ws  = (float*)d_ws;
  uint4* xnf = (uint4*)((char*)d_ws + 32768);

  k_norm_input<<<BROWS, 64, 0, stream>>>(input, xnf, ws);
  k_gemm<<<NBLK, 768, 0, stream>>>(xnf, weight, bias, ws);
  k_label<<<BROWS, 64, 0, stream>>>(input, weight, label, bias, ws);
  k_final<<<1, 64, 0, stream>>>(ws, out);
}

// Round 13
// 140.215 us; speedup vs baseline: 1.4064x; 1.0255x over previous
//
#include <hip/hip_runtime.h>
#include <hip/hip_bf16.h>
#include <stdint.h>

// ---- problem constants ----
#define C_CLS  100000
#define DDIM   512
#define BROWS  512
#define BN     128         // classes per tile
#define EPSN   1e-5f
#define NBLK   256         // persistent blocks (1 per CU)
#define AS1    __attribute__((address_space(1)))
#define AS3    __attribute__((address_space(3)))

typedef __attribute__((ext_vector_type(8))) short short8;
typedef __attribute__((ext_vector_type(4))) float f32x4;

// d_ws float layout:
//   [0    .. 4096)  : 256 gemm accumulation slots, stride 16 floats
//   [4096 .. 5120)  : 64 label accumulation slots, stride 16 floats
//   byte 32768 ...  : xnf — bf16 A in MFMA fragment layout (512 KB)

__device__ inline unsigned pk2(float a, float b) {
  __hip_bfloat162 h = __float22bfloat162_rn(make_float2(a, b));
  unsigned u; __builtin_memcpy(&u, &h, 4); return u;
}

// Normalize each input row -> bf16, fragment order:
// cell idx (16B) = (s*32 + r16)*64 + khalf*16 + row; s=k>>5, r16=b>>4,
// khalf=(k>>3)&3, row=b&15. Also zeroes the ws accumulation slots.
__global__ void __launch_bounds__(64) k_norm_input(const float* __restrict__ in,
                                                   uint4* __restrict__ xnf,
                                                   float* __restrict__ ws) {
  int b = blockIdx.x;
  int lane = threadIdx.x;              // lane covers k = lane*8 .. +7
  if (lane == 0) {
    if (b < 256) ws[b * 16] = 0.f;
    else if (b < 320) ws[4096 + (b - 256) * 16] = 0.f;
  }
  const float4* row = (const float4*)(in + b * DDIM);
  float4 v0 = row[lane * 2];
  float4 v1 = row[lane * 2 + 1];
  float ss = v0.x*v0.x + v0.y*v0.y + v0.z*v0.z + v0.w*v0.w
           + v1.x*v1.x + v1.y*v1.y + v1.z*v1.z + v1.w*v1.w;
#pragma unroll
  for (int o = 32; o >= 1; o >>= 1) ss += __shfl_xor(ss, o, 64);
  float sc = 1.f / fmaxf(sqrtf(ss), EPSN);
  uint4 o4;
  o4.x = pk2(v0.x*sc, v0.y*sc);
  o4.y = pk2(v0.z*sc, v0.w*sc);
  o4.z = pk2(v1.x*sc, v1.y*sc);
  o4.w = pk2(v1.z*sc, v1.w*sc);
  int idx = ((lane >> 2) * 32 + (b >> 4)) * 64 + (lane & 3) * 16 + (b & 15);
  xnf[idx] = o4;
}

// Fused GEMM + loss, producer/consumer wave specialization.
// 768 threads: waves 0..7 consumers (wave tile 64 rows x 128 cls, acc 128),
// waves 8..11 producers (W f32 HBM->reg->wsq+cvt->bf16 frag LDS, 2-step reg
// pipeline, counted vmcnt(4)). Consumers DMA their own A rows (L2-resident
// xnf) into a 3-slot LDS ring via global_load_lds with counted vmcnt(4) —
// A-only vmem queue, so counted waits are exact. One barrier per K32-step,
// continuous cadence across tiles; per-tile loss epilogue inside one interval.
__global__ void __launch_bounds__(768, 3)
k_gemm(const uint4* __restrict__ xnf, const float* __restrict__ wt,
       const float* __restrict__ bias, float* __restrict__ ws) {
  __shared__ __align__(16) unsigned char sA[3][32768];  // bf16 A frag cells
  __shared__ __align__(16) unsigned char sW[4][8192];   // bf16 W frag cells
  __shared__ float sNsq[2][BN];

  const int tid  = threadIdx.x;
  const int lane = tid & 63;
  const int wv   = tid >> 6;                   // 0..11
  const int nt   = (blockIdx.x < 14) ? 4 : 3;  // 782 = 14*4 + 242*3
  const int NS   = nt * 16;

  if (wv >= 8) {
    // ---------------- producers: W stream ----------------
    const int pw  = wv - 8;                    // 0..3
    const int row = pw * 32 + (lane >> 1);     // local class 0..127 (fixed/lane)
    const int kh  = lane & 1;                  // 16-float half of the 32-k step
    const int swz = (row >> 1) & 3;
    const int co0 = ((kh * 2 + 0) ^ swz) * 16;
    const int co1 = ((kh * 2 + 1) ^ swz) * 16;
    float wsq = 0.f;

    auto load4 = [&](float4* r, int c) {       // 4 float4 = lane's 16 floats
      int it = c >> 4, s = c & 15;
      int cls = (blockIdx.x + it * NBLK) * BN + row;
      if (cls >= C_CLS) cls = C_CLS - 1;       // clamp; masked in epilogue
      const float4* p = (const float4*)(wt + (size_t)cls * DDIM + s * 32 + kh * 16);
      r[0] = p[0]; r[1] = p[1]; r[2] = p[2]; r[3] = p[3];
    };
    auto cvtw = [&](const float4* r, int c) {
#pragma unroll
      for (int q = 0; q < 4; q++)
        wsq += r[q].x*r[q].x + r[q].y*r[q].y + r[q].z*r[q].z + r[q].w*r[q].w;
      unsigned char* base = sW[c & 3] + row * 64;
      uint4 u0, u1;
      u0.x = pk2(r[0].x, r[0].y); u0.y = pk2(r[0].z, r[0].w);
      u0.z = pk2(r[1].x, r[1].y); u0.w = pk2(r[1].z, r[1].w);
      u1.x = pk2(r[2].x, r[2].y); u1.y = pk2(r[2].z, r[2].w);
      u1.z = pk2(r[3].x, r[3].y); u1.w = pk2(r[3].z, r[3].w);
      *(uint4*)(base + co0) = u0;
      *(uint4*)(base + co1) = u1;
      if ((c & 15) == 15) {                    // tile's norms complete
        float t = wsq + __shfl_xor(wsq, 1, 64);
        if (kh == 0) sNsq[(c >> 4) & 1][row] = t;
        wsq = 0.f;
      }
    };
    auto pbar = [&]() {
      asm volatile("s_waitcnt lgkmcnt(0)" ::: "memory");
      __builtin_amdgcn_s_barrier();
    };

    float4 rA[4], rB[4];
    load4(rA, 0);                              // c=0 in flight
    load4(rB, 1);                              // c=1 in flight
    asm volatile("s_waitcnt vmcnt(4)" ::: "memory");
    cvtw(rA, 0);                               // W(0) -> ring 0
    pbar();                                    // prologue barrier

#pragma unroll 1
    for (int g = 0; g < NS; g += 2) {
      {                                        // step g: cvt c=g+1 (in rB)
        int c = g + 1;
        if (c < NS) {
          if (c + 1 < NS) { load4(rA, c + 1);
            asm volatile("s_waitcnt vmcnt(4)" ::: "memory"); }
          else { asm volatile("s_waitcnt vmcnt(0)" ::: "memory"); }
          cvtw(rB, c);
        }
        pbar();
      }
      {                                        // step g+1: cvt c=g+2 (in rA)
        int c = g + 2;
        if (c < NS) {
          if (c + 1 < NS) { load4(rB, c + 1);
            asm volatile("s_waitcnt vmcnt(4)" ::: "memory"); }
          else { asm volatile("s_waitcnt vmcnt(0)" ::: "memory"); }
          cvtw(rA, c);
        }
        pbar();
      }
    }
  } else {
    // ---------------- consumers: MFMA ----------------
    const int r16 = lane & 15;
    const int ko  = lane >> 4;
    const uint4* asrc0 = xnf + (wv * 4) * 64 + lane;   // + s*2048 + i*64
    const float bv = bias[0];
    float lsum = 0.f;

    auto dmaA = [&](int g) {                   // 4 x 1KB, coalesced, linear dest
      const uint4* src = asrc0 + (g & 15) * 2048;
      unsigned char* dst = sA[g % 3] + wv * 4096;
#pragma unroll
      for (int i = 0; i < 4; ++i)
        __builtin_amdgcn_global_load_lds(
            (const AS1 unsigned int*)(src + i * 64),
            (AS3 unsigned int*)(dst + i * 1024), 16, 0, 0);
    };

    f32x4 acc[4][8];
#pragma unroll
    for (int i = 0; i < 4; ++i)
#pragma unroll
      for (int j = 0; j < 8; ++j) acc[i][j] = (f32x4)(0.f);

    dmaA(0);
    dmaA(1);
    __builtin_amdgcn_s_barrier();              // matches producer prologue

#pragma unroll 1
    for (int g = 0; g < NS; ++g) {
      bool more = (g + 2 < NS);
      if (more) dmaA(g + 2);
      const unsigned char* Ab = sA[g % 3];
      const unsigned char* Wb = sW[g & 3];
      short8 af[4];
#pragma unroll
      for (int i = 0; i < 4; ++i)
        af[i] = *(const short8*)(Ab + ((wv * 4 + i) * 64 + lane) * 16);
      __builtin_amdgcn_s_setprio(1);
#pragma unroll
      for (int j = 0; j < 8; ++j) {
        int cls = j * 16 + r16;
        short8 wf = *(const short8*)(Wb + (cls * 4 + (ko ^ ((cls >> 1) & 3))) * 16);
#pragma unroll
        for (int i = 0; i < 4; ++i)
          acc[i][j] = __builtin_amdgcn_mfma_f32_16x16x32_bf16(af[i], wf, acc[i][j], 0, 0, 0);
      }
      __builtin_amdgcn_s_setprio(0);
      __builtin_amdgcn_sched_barrier(0);
      if (more) asm volatile("s_waitcnt vmcnt(4)" ::: "memory");
      else      asm volatile("s_waitcnt vmcnt(0)" ::: "memory");
      __builtin_amdgcn_s_barrier();
      __builtin_amdgcn_sched_barrier(0);

      if ((g & 15) == 15) {
        // ---- tile epilogue (inside one barrier interval) ----
        const int it = g >> 4;
        const int cb = (blockIdx.x + it * NBLK) * BN;
        const float* nsq = sNsq[it & 1];
#pragma unroll
        for (int j = 0; j < 8; ++j) {
          float t = nsq[j * 16 + r16];
          float s64 = 64.f / fmaxf(sqrtf(t), EPSN);  // fold S and 1/||w||
          bool valid = (cb + j * 16 + r16) < C_CLS;
#pragma unroll
          for (int i = 0; i < 4; ++i) {
#pragma unroll
            for (int e = 0; e < 4; ++e) {
              // x = 64*cos - bias <= ~51: upper clamp provably inactive;
              // lower clip irrelevant (underflow). log1p(z)~=z-z^2/2, z<=1/32.
              float x = fmaf(acc[i][j][e], s64, -bv);
              float z = __expf(x);
              float l = fmaf(-0.5f * z, z, z);
              if (z > 0.03125f) l = __logf(1.f + z); // rare (~1e-4)
              lsum += valid ? l : 0.f;
            }
            acc[i][j] = (f32x4)(0.f);
          }
        }
      }
    }
#pragma unroll
    for (int o = 32; o >= 1; o >>= 1) lsum += __shfl_xor(lsum, o, 64);
    if (lane == 0)
      atomicAdd(&ws[(((blockIdx.x << 3) + wv) & 255) * 16], lsum);
  }
}

// Label correction: replace n_loss(b, label_b) by p_loss(b, label_b), full f32.
__global__ void __launch_bounds__(64) k_label(const float* __restrict__ in,
                                              const float* __restrict__ wt,
                                              const int* __restrict__ label,
                                              const float* __restrict__ bias,
                                              float* __restrict__ ws) {
  int b = blockIdx.x;
  int lane = threadIdx.x;
  int c = label[b];
  const float4* xr = (const float4*)(in + b * DDIM);
  const float4* wr = (const float4*)(wt + (size_t)c * DDIM);
  float dt = 0.f, sx = 0.f, sw = 0.f;
#pragma unroll
  for (int i = 0; i < 2; i++) {
    float4 x = xr[lane * 2 + i];
    float4 w = wr[lane * 2 + i];
    dt += x.x*w.x + x.y*w.y + x.z*w.z + x.w*w.w;
    sx += x.x*x.x + x.y*x.y + x.z*x.z + x.w*x.w;
    sw += w.x*w.x + w.y*w.y + w.z*w.z + w.w*w.w;
  }
#pragma unroll
  for (int o = 32; o >= 1; o >>= 1) {
    dt += __shfl_xor(dt, o, 64);
    sx += __shfl_xor(sx, o, 64);
    sw += __shfl_xor(sw, o, 64);
  }
  if (lane == 0) {
    float bv = bias[0];
    float cosv = dt / (fmaxf(sqrtf(sx), EPSN) * fmaxf(sqrtf(sw), EPSN));
    float cp = 64.f * (cosv - 0.4f) - bv;
    cp = fminf(fmaxf(cp, -64.f), 64.f);
    float pl = log1pf(expf(-cp));
    float cn = 64.f * cosv - bv;
    cn = fminf(fmaxf(cn, -64.f), 64.f);
    float nl = log1pf(expf(cn));
    atomicAdd(&ws[4096 + (b & 63) * 16], pl - nl);
  }
}

// Merge the 256 gemm slots + 64 label slots, scale by 1/B.
__global__ void __launch_bounds__(64) k_final(const float* __restrict__ ws,
                                              float* __restrict__ out) {
  int lane = threadIdx.x;
  float s = ws[lane * 16] + ws[(lane + 64) * 16]
          + ws[(lane + 128) * 16] + ws[(lane + 192) * 16]
          + ws[4096 + lane * 16];
#pragma unroll
  for (int o = 32; o >= 1; o >>= 1) s += __shfl_xor(s, o, 64);
  if (lane == 0) out[0] = s * (1.f / 512.f);
}

extern "C" void kernel_launch(void* const* d_in, const int* in_sizes, int n_in,
                              void* d_out, int out_size, void* d_ws, size_t ws_size,
                              hipStream_t stream) {
  const float* input  = (const float*)d_in[0];
  const int*   label  = (const int*)d_in[1];
  const float* weight = (const float*)d_in[2];
  const float* bias   = (const float*)d_in[3];
  float* out = (float*)d_out;
  float* ws  = (float*)d_ws;
  uint4* xnf = (uint4*)((char*)d_ws + 32768);

  k_norm_input<<<BROWS, 64, 0, stream>>>(input, xnf, ws);
  k_gemm<<<NBLK, 768, 0, stream>>>(xnf, weight, bias, ws);
  k_label<<<BROWS, 64, 0, stream>>>(input, weight, label, bias, ws);
  k_final<<<1, 64, 0, stream>>>(ws, out);
}